// Round 8
// baseline (304.125 us; speedup 1.0000x reference)
//
#include <hip/hip_runtime.h>
#include <hip/hip_bf16.h>

#define EPSV 1e-5f

typedef __attribute__((ext_vector_type(8))) short bf16x8;
typedef __attribute__((ext_vector_type(16))) float f32x16;

static __device__ __forceinline__ short f2bf(float f) {
    __hip_bfloat16 b = __float2bfloat16(f);
    return __builtin_bit_cast(short, b);
}

typedef __attribute__((address_space(3))) void lds_t;
typedef const __attribute__((address_space(1))) void gbl_t;
static __device__ __forceinline__ void glds16(const void* g, void* l) {
    __builtin_amdgcn_global_load_lds((gbl_t*)g, (lds_t*)l, 16, 0, 0);
}

// Fused: blocks [0, EBL) run the edge MLP (z generation); blocks [EBL, ...) repack w2 -> w2a.
// w2a[((h*CH + c)*2 + rowg)*512 + lane*8 + j] = bf16(w2[h][i*64+o]),
//   o = rowg*32 + (lane&31), i = c*16 + (lane>>5)*8 + j ; h==64 slab = b2; h==65 slab = 0 pad.
// zge[e*64 + h] = bf16(relu(b1[h] + ea@w1))
template <int CIN>
__global__ void k_edge_prep(const float* __restrict__ ea, const float* __restrict__ w1,
                            const float* __restrict__ b1, short* __restrict__ zge, int E, int EBL,
                            const float* __restrict__ w2, const float* __restrict__ b2,
                            short* __restrict__ w2a) {
    constexpr int CH = CIN / 16;
    int t = threadIdx.x;
    if ((int)blockIdx.x >= EBL) {
        int idx = ((int)blockIdx.x - EBL) * 256 + t;
        int total = 66 * CH * 1024;          // 66 slabs: 64 w2 + b2 + zero pad
        if (idx >= total) return;
        int j = idx & 7;
        int l = (idx >> 3) & 63;
        int rowg = (idx >> 9) & 1;
        int c = (idx >> 10) % CH;
        int h = idx / (CH * 1024);
        int o = rowg * 32 + (l & 31);
        int i = c * 16 + (l >> 5) * 8 + j;
        float v = 0.f;
        if (h < 64) v = w2[(size_t)h * (CIN * 64) + i * 64 + o];
        else if (h == 64) v = b2[i * 64 + o];
        w2a[idx] = f2bf(v);
        return;
    }
    __shared__ float sEA[64][17];
    int e0 = blockIdx.x * 64;
    for (int f = t; f < 64 * 16; f += 256) {
        int e = f >> 4, i = f & 15;
        int ge = e0 + e;
        sEA[e][i] = (ge < E) ? ea[(size_t)ge * 16 + i] : 0.f;
    }
    __syncthreads();
    int lane = t & 63, w = t >> 6;
    int ge = e0 + lane;
    union { bf16x8 v[2]; short s[16]; } ov;
    #pragma unroll
    for (int hh = 0; hh < 16; ++hh) {
        int h = w * 16 + hh;
        float acc = b1[h];
        #pragma unroll
        for (int i = 0; i < 16; ++i) acc += sEA[lane][i] * w1[i * 64 + h];
        ov.s[hh] = f2bf(fmaxf(acc, 0.f));
    }
    if (ge < E) {
        short* base = zge + (size_t)ge * 64 + w * 16;
        *reinterpret_cast<bf16x8*>(base) = ov.v[0];
        *reinterpret_cast<bf16x8*>(base + 8) = ov.v[1];
    }
}

// layer-1 fused prep: agg init (root GEMM on x) + x -> bf16
__global__ void k_pre1(const float* __restrict__ x, const float* __restrict__ root,
                       const float* __restrict__ bias, short* __restrict__ xb,
                       float* __restrict__ out, int N) {
    int idx = blockIdx.x * blockDim.x + threadIdx.x;
    int n = idx >> 6, o = idx & 63;
    if (n >= N) return;
    float acc = bias[o];
    #pragma unroll
    for (int i = 0; i < 32; ++i) acc += x[(size_t)n * 32 + i] * root[i * 64 + o];
    out[(size_t)n * 64 + o] = acc;
    if (o < 32) xb[(size_t)n * 32 + o] = f2bf(x[(size_t)n * 32 + o]);
}

// MFMA msg v6 (m97 structure): global_load_lds double-buffered chunks of 2 h-slabs,
// ds_read_b128 fragments -> MFMA; full h-range per block (no h-split).
template <int CIN>
__global__ __launch_bounds__(256, 3) void k_msg(const short* __restrict__ zge,
                                                const short* __restrict__ xb,
                                                const int* __restrict__ src,
                                                const int* __restrict__ dstv,
                                                const short* __restrict__ w2a,
                                                float* __restrict__ agg, int E) {
    constexpr int CH = CIN / 16;
    constexpr int SLAB = CH * 2 * 512;     // shorts per h-slab (both rowg)
    constexpr int CHUNK = 2 * SLAB;        // shorts per chunk (2 slabs)
    constexpr int CALLS = (CHUNK * 2) / 4096;  // staging rounds (4KB per round)
    __shared__ short sA[2][CHUNK] __attribute__((aligned(16)));
    __shared__ float sT[64][66];
    int t = threadIdx.x;
    int e0 = blockIdx.x * 64;
    int lane = t & 63, w = t >> 6;
    int rowg = w >> 1;            // o half
    int colg = w & 1;             // e half
    int kg = lane >> 5, l31 = lane & 31;
    int ecol = colg * 32 + l31;
    int ge = e0 + ecol;
    int gec = min(ge, E - 1);

    auto stage = [&](int buf, int chunk) {
        const short* g = w2a + (size_t)chunk * CHUNK;
        #pragma unroll
        for (int r = 0; r < CALLS; ++r) {
            int off = r * 2048 + w * 512;
            glds16(g + off + lane * 8, &sA[buf][off]);
        }
    };

    stage(0, 0);

    // B operand: x[src(e)] fragments, fixed across all h
    int srow = src[gec];
    bf16x8 xB[CH];
    #pragma unroll
    for (int c = 0; c < CH; ++c)
        xB[c] = *reinterpret_cast<const bf16x8*>(xb + (size_t)srow * CIN + c * 16 + kg * 8);

    // z row for this lane's edge: 64 bf16 = 8 x 16B coalesced = 32 packed u32 pairs
    union { bf16x8 v[8]; unsigned u[32]; } zr;
    {
        const short* zb = zge + (size_t)gec * 64;
        #pragma unroll
        for (int c = 0; c < 8; ++c)
            zr.v[c] = *reinterpret_cast<const bf16x8*>(zb + c * 8);
    }

    f32x16 zero;
    #pragma unroll
    for (int r = 0; r < 16; ++r) zero[r] = 0.f;
    asm volatile("" : "+v"(zero));   // opaque zero tuple: no per-iter v_mov

    f32x16 acc = zero;

    __syncthreads();   // chunk 0 resident (vmcnt drain + barrier)

    int cur = 0;
    #pragma unroll 1
    for (int ci = 0; ci < 33; ++ci) {
        if (ci < 32) stage(cur ^ 1, ci + 1);   // prefetch next chunk; flies during compute
        const short* base = &sA[cur][0];
        if (ci < 32) {
            bf16x8 a0[CH], a1[CH];
            #pragma unroll
            for (int c = 0; c < CH; ++c) {
                a0[c] = *reinterpret_cast<const bf16x8*>(base + (c * 2 + rowg) * 512 + lane * 8);
                a1[c] = *reinterpret_cast<const bf16x8*>(base + SLAB + (c * 2 + rowg) * 512 + lane * 8);
            }
            unsigned zp = zr.u[ci];
            float zlo = __builtin_bit_cast(float, zp << 16);
            float zhi = __builtin_bit_cast(float, zp & 0xffff0000u);
            f32x16 t0 = __builtin_amdgcn_mfma_f32_32x32x16_bf16(a0[0], xB[0], zero, 0, 0, 0);
            f32x16 t1 = __builtin_amdgcn_mfma_f32_32x32x16_bf16(a1[0], xB[0], zero, 0, 0, 0);
            #pragma unroll
            for (int c = 1; c < CH; ++c) {
                t0 = __builtin_amdgcn_mfma_f32_32x32x16_bf16(a0[c], xB[c], t0, 0, 0, 0);
                t1 = __builtin_amdgcn_mfma_f32_32x32x16_bf16(a1[c], xB[c], t1, 0, 0, 0);
            }
            #pragma unroll
            for (int r = 0; r < 16; ++r) {
                acc[r] = fmaf(zlo, t0[r], acc[r]);
                acc[r] = fmaf(zhi, t1[r], acc[r]);
            }
        } else {  // b2 slab (h==64, z=1); slab 65 staged (zero pad) but never consumed
            bf16x8 a0[CH];
            #pragma unroll
            for (int c = 0; c < CH; ++c)
                a0[c] = *reinterpret_cast<const bf16x8*>(base + (c * 2 + rowg) * 512 + lane * 8);
            f32x16 tb = __builtin_amdgcn_mfma_f32_32x32x16_bf16(a0[0], xB[0], zero, 0, 0, 0);
            #pragma unroll
            for (int c = 1; c < CH; ++c)
                tb = __builtin_amdgcn_mfma_f32_32x32x16_bf16(a0[c], xB[c], tb, 0, 0, 0);
            #pragma unroll
            for (int r = 0; r < 16; ++r) acc[r] += tb[r];
        }
        __syncthreads();   // drains prefetch (vmcnt0) -> next chunk ready; protects buf reuse
        cur ^= 1;
    }

    // transpose via LDS: each wave writes a disjoint 32x32 quadrant
    #pragma unroll
    for (int r = 0; r < 16; ++r) {
        int o = (r & 3) + 8 * (r >> 2) + 4 * kg + 32 * rowg;
        sT[o][ecol] = acc[r];
    }
    __syncthreads();

    // coalesced scatter: 64 lanes = 64 consecutive o for one edge
    for (int e = w; e < 64; e += 4) {
        int geo = e0 + e;
        if (geo < E) {
            int d = dstv[geo];
            atomicAdd(&agg[(size_t)d * 64 + lane], sT[lane][e]);
        }
    }
}

// fused LayerNorm+ReLU -> bf16 (for next msg) AND next layer's root GEMM (agg init).
__global__ void k_ln_root(const float* __restrict__ hin, const float* __restrict__ g,
                          const float* __restrict__ b, const float* __restrict__ root,
                          const float* __restrict__ bias, short* __restrict__ xbout,
                          float* __restrict__ aggnext, int N) {
    __shared__ float sh[4][64];
    int w = threadIdx.x >> 6, lane = threadIdx.x & 63;
    int n = blockIdx.x * 4 + w;
    bool valid = n < N;
    int nc = valid ? n : (N - 1);
    float v = hin[(size_t)nc * 64 + lane];
    float s = v;
    #pragma unroll
    for (int d = 32; d > 0; d >>= 1) s += __shfl_xor(s, d, 64);
    float mean = s * (1.f / 64.f);
    float dv = v - mean;
    float s2 = dv * dv;
    #pragma unroll
    for (int d = 32; d > 0; d >>= 1) s2 += __shfl_xor(s2, d, 64);
    float var = s2 * (1.f / 64.f);
    float o = fmaxf(dv * rsqrtf(var + EPSV) * g[lane] + b[lane], 0.f);
    if (valid) xbout[(size_t)n * 64 + lane] = f2bf(o);
    sh[w][lane] = o;
    __syncthreads();
    float acc = bias[lane];
    #pragma unroll 8
    for (int i = 0; i < 64; ++i) acc = fmaf(sh[w][i], root[i * 64 + lane], acc);
    if (valid) aggnext[(size_t)n * 64 + lane] = acc;
}

// plain LayerNorm+ReLU in place (final layer)
__global__ void k_ln(float* __restrict__ h, const float* __restrict__ g, const float* __restrict__ b, int N) {
    int n = blockIdx.x * 4 + (threadIdx.x >> 6);
    int lane = threadIdx.x & 63;
    if (n >= N) return;
    float v = h[(size_t)n * 64 + lane];
    float s = v;
    #pragma unroll
    for (int d = 32; d > 0; d >>= 1) s += __shfl_xor(s, d, 64);
    float mean = s * (1.f / 64.f);
    float dv = v - mean;
    float s2 = dv * dv;
    #pragma unroll
    for (int d = 32; d > 0; d >>= 1) s2 += __shfl_xor(s2, d, 64);
    float var = s2 * (1.f / 64.f);
    h[(size_t)n * 64 + lane] = fmaxf(dv * rsqrtf(var + EPSV) * g[lane] + b[lane], 0.f);
}

// fused mean-pool (binary search on sorted batch) + MLP head; 4 waves/graph
__global__ void k_pool_head(const float* __restrict__ h, const int* __restrict__ batch,
                            const float* __restrict__ fc1w, const float* __restrict__ fc1b,
                            const float* __restrict__ fc2w, const float* __restrict__ fc2b,
                            float* __restrict__ out, int N) {
    __shared__ float part[4][64];
    __shared__ float sh[64];
    __shared__ float sh2[32];
    int g = blockIdx.x;
    int t = threadIdx.x, lane = t & 63, w = t >> 6;
    int lo = 0, hi = N;
    while (lo < hi) { int m = (lo + hi) >> 1; if (batch[m] < g) lo = m + 1; else hi = m; }
    int s0 = lo;
    hi = N;
    while (lo < hi) { int m = (lo + hi) >> 1; if (batch[m] < g + 1) lo = m + 1; else hi = m; }
    int s1 = lo;
    float s = 0.f;
    for (int n = s0 + w; n < s1; n += 4) s += h[(size_t)n * 64 + lane];
    part[w][lane] = s;
    __syncthreads();
    if (t < 64) {
        float c = fmaxf((float)(s1 - s0), 1.f);
        sh[t] = (part[0][t] + part[1][t] + part[2][t] + part[3][t]) / c;
    }
    __syncthreads();
    if (t < 32) {
        float a = fc1b[t];
        #pragma unroll
        for (int o = 0; o < 64; ++o) a += sh[o] * fc1w[o * 32 + t];
        sh2[t] = fmaxf(a, 0.f);
    }
    __syncthreads();
    if (t == 0) {
        float a = fc2b[0];
        #pragma unroll
        for (int j = 0; j < 32; ++j) a += sh2[j] * fc2w[j];
        out[g] = a;
    }
}

extern "C" void kernel_launch(void* const* d_in, const int* in_sizes, int n_in,
                              void* d_out, int out_size, void* d_ws, size_t ws_size,
                              hipStream_t stream) {
    const float* x     = (const float*)d_in[0];
    const int*   ei    = (const int*)d_in[1];
    const float* ea    = (const float*)d_in[2];
    const int*   batch = (const int*)d_in[3];
    int E = in_sizes[1] / 2;
    int N = in_sizes[3];
    int G = out_size;  // DOUT = 1
    const int* src  = ei;
    const int* dstv = ei + E;

    const float* P[24];
    for (int i = 0; i < 24; ++i) P[i] = (const float*)d_in[4 + i];
    const float* fc1w = (const float*)d_in[28];
    const float* fc1b = (const float*)d_in[29];
    const float* fc2w = (const float*)d_in[30];
    const float* fc2b = (const float*)d_in[31];

    // workspace layout
    float* hA  = (float*)d_ws;                 // N*64 f32
    float* hB  = hA + (size_t)N * 64;          // N*64 f32
    short* zge = (short*)(hB + (size_t)N * 64);// E*64 bf16 (z rows)
    short* xbA = zge + (size_t)E * 64;         // N*64 bf16
    short* xbB = xbA + (size_t)N * 64;         // N*64 bf16
    short* w2a = xbB + (size_t)N * 64;         // 66 slabs * CH*1024 bf16 (66th = zero pad)

    int ebl   = (E + 63) / 64;
    int n64   = (N * 64 + 255) / 256;
    int nln   = (N + 3) / 4;
    int pb64  = (66 * 4 * 1024 + 255) / 256;   // prep blocks, CIN=64
    int pb32  = (66 * 2 * 1024 + 255) / 256;   // prep blocks, CIN=32

    // ---- layer 1 (cin = 32) ----
    k_edge_prep<32><<<ebl + pb32, 256, 0, stream>>>(ea, P[0], P[1], zge, E, ebl, P[2], P[3], w2a);
    k_pre1<<<n64, 256, 0, stream>>>(x, P[4], P[5], xbA, hA, N);
    k_msg<32><<<ebl, 256, 0, stream>>>(zge, xbA, src, dstv, w2a, hA, E);

    // ---- layer 2 (cin = 64) ----
    k_edge_prep<64><<<ebl + pb64, 256, 0, stream>>>(ea, P[8], P[9], zge, E, ebl, P[10], P[11], w2a);
    k_ln_root<<<nln, 256, 0, stream>>>(hA, P[6], P[7], P[12], P[13], xbB, hB, N);
    k_msg<64><<<ebl, 256, 0, stream>>>(zge, xbB, src, dstv, w2a, hB, E);

    // ---- layer 3 (cin = 64) ----
    k_edge_prep<64><<<ebl + pb64, 256, 0, stream>>>(ea, P[16], P[17], zge, E, ebl, P[18], P[19], w2a);
    k_ln_root<<<nln, 256, 0, stream>>>(hB, P[14], P[15], P[20], P[21], xbA, hA, N);
    k_msg<64><<<ebl, 256, 0, stream>>>(zge, xbA, src, dstv, w2a, hA, E);
    k_ln<<<nln, 256, 0, stream>>>(hA, P[22], P[23], N);

    // ---- fused pool + head ----
    k_pool_head<<<G, 256, 0, stream>>>(hA, batch, fc1w, fc1b, fc2w, fc2b, (float*)d_out, N);
}